// Round 15
// baseline (261.575 us; speedup 1.0000x reference)
//
#include <hip/hip_runtime.h>

typedef float  f4v    __attribute__((ext_vector_type(4)));
typedef __bf16 bf16x8 __attribute__((ext_vector_type(8)));
typedef __bf16 bf16x4 __attribute__((ext_vector_type(4)));

#define PCAP  16384   // max pair rows (clamp bound; actual A~127 -> Ppad 8192)
#define LDQ   16384
#define CH    1024
#define KI    2048    // interleaved K (diff/mul alternating)
#define KIT   32      // K iterations (BK=64)

__device__ __forceinline__ int offA(int r, int A) { return r * A - ((r * (r - 1)) >> 1); }

// ballot-scan of mask -> act[], A
__device__ __forceinline__ int mask_scan(const int* am, int t, int* act,
                                         unsigned long long* wm, int* wred) {
    int wave = t >> 6, lane = t & 63;
    int a = am[t];
    int sv = a;
#pragma unroll
    for (int d = 32; d; d >>= 1) sv += __shfl_down(sv, d);
    if (lane == 0) wred[wave] = sv;
    __syncthreads();
    int s = wred[0] + wred[1] + wred[2] + wred[3];
    int keep = (t != 0 && t != s && a != 0) ? 1 : 0;
    unsigned long long bm = __ballot(keep);
    if (lane == 0) wm[wave] = bm;
    __syncthreads();
    int base = 0, A = 0;
#pragma unroll
    for (int w = 0; w < 4; w++) {
        int pc = __popcll(wm[w]);
        if (w < wave) base += pc;
        A += pc;
    }
    if (keep) act[base + __popcll(bm & ((1ull << lane) - 1ull))] = t;
    __syncthreads();
    return A;
}

// ---------------- prep kernel (featT generation REMOVED -> fused into gemm) ---------
#define PB_CVTA   0       // 512: A1p interleaved bf16 conv of conv1_w
#define PB_K2     512     // 256: K2w[64][1024]
#define PB_QCONST 768     // 49
#define PB_ZERO   817     // 797: zero Q + Qs (contiguous)
#define PB_SCAN   1614    // 1: rank/counts/act export
#define PB_HID    1615    // 256: hid gemv
#define PB_TOTAL  1871

__global__ void k_prep(const float* __restrict__ att, const int* __restrict__ am,
                       const float* __restrict__ c1w, const float* __restrict__ c2w,
                       const float* __restrict__ c1b,
                       const float* __restrict__ pooled, const float* __restrict__ lin1_w,
                       const float* __restrict__ lin1_b,
                       int* rank, int* counts, int* actg, __bf16* A1p, __bf16* K2w,
                       float* Qc, float* Qzero, float* hid) {
    int b = blockIdx.x, t = threadIdx.x;

    if (b < PB_K2) {
        int gid = b * 256 + t;              // 131072
        int o = gid >> 7, cw = (gid & 127) * 8;
        const float* wd = &c1w[o * 2048 + cw];
        const float* wmu = &c1w[o * 2048 + 1024 + cw];
        float4 d0 = *(const float4*)wd,  d1 = *(const float4*)(wd + 4);
        float4 m0 = *(const float4*)wmu, m1 = *(const float4*)(wmu + 4);
        bf16x8 v0, v1;
        v0[0] = (__bf16)d0.x; v0[1] = (__bf16)m0.x; v0[2] = (__bf16)d0.y; v0[3] = (__bf16)m0.y;
        v0[4] = (__bf16)d0.z; v0[5] = (__bf16)m0.z; v0[6] = (__bf16)d0.w; v0[7] = (__bf16)m0.w;
        v1[0] = (__bf16)d1.x; v1[1] = (__bf16)m1.x; v1[2] = (__bf16)d1.y; v1[3] = (__bf16)m1.y;
        v1[4] = (__bf16)d1.z; v1[5] = (__bf16)m1.z; v1[6] = (__bf16)d1.w; v1[7] = (__bf16)m1.w;
        *(bf16x8*)&A1p[o * 2048 + 2 * cw] = v0;
        *(bf16x8*)&A1p[o * 2048 + 2 * cw + 8] = v1;
    } else if (b < PB_QCONST) {
        int e = (b - PB_K2) * 256 + t;      // 65536 = 64*1024
        int trow = e >> 10, o = e & 1023;
        K2w[e] = (trow < 49) ? (__bf16)c2w[o * 49 + trow] : (__bf16)0.0f;
    } else if (b < PB_ZERO) {
        __shared__ float sh[256];
        int tap = b - PB_QCONST;
        float s = 0.f;
        for (int o = t; o < CH; o += 256) s += c2w[o * 49 + tap] * fmaxf(c1b[o], 0.f);
        sh[t] = s; __syncthreads();
        for (int d = 128; d; d >>= 1) { if (t < d) sh[t] += sh[t + d]; __syncthreads(); }
        if (t == 0) Qc[tap] = sh[0];
    } else if (b < PB_SCAN) {
        int idx = (b - PB_ZERO) * 256 + t;  // 203840 float4 = Q(49*16384) + Qs(49*256)
        if (idx < 203840) {
            float4 zv = {0.f, 0.f, 0.f, 0.f};
            ((float4*)Qzero)[idx] = zv;
        }
    } else if (b == PB_SCAN) {
        __shared__ int act[256];
        __shared__ unsigned long long wm[4];
        __shared__ int wred[4];
        int A = mask_scan(am, t, act, wm, wred);
        int wave = t >> 6, lane = t & 63;
        int s = wred[0] + wred[1] + wred[2] + wred[3];
        int keep = (t != 0 && t != s && am[t] != 0) ? 1 : 0;
        int base = 0;
#pragma unroll
        for (int w = 0; w < 4; w++) if (w < wave) base += __popcll(wm[w]);
        unsigned long long bm = wm[wave];
        rank[t] = keep ? (base + __popcll(bm & ((1ull << lane) - 1ull))) : -1;
        actg[t] = (t < A) ? act[t] : 0;     // export kept indices for fused gemm
        if (t == 0) {
            int P = (A * (A + 1)) >> 1;
            int Pp = ((P + 127) >> 7) << 7;
            if (Pp > PCAP) Pp = PCAP;
            counts[0] = A; counts[1] = P; counts[2] = Pp;
        }
    } else {
        int o = (b - PB_HID) * 4 + (t >> 6);
        int lane = t & 63;
        const float* row = lin1_w + (size_t)o * CH;
        float s = 0.f;
        for (int c = lane; c < CH; c += 64) s += pooled[c] * row[c];
        for (int d = 32; d; d >>= 1) s += __shfl_down(s, d);
        if (lane == 0) hid[o] = s + lin1_b[o];
    }
}

// ---------------- GEMM with FUSED B-generation: 512 threads, 128M x 128N, BK=64 -------
// B tiles (|zi-zj|, zi*zj interleaved) are generated on the fly from att (1 MB,
// L2-resident) instead of a 33.5 MB featT round-trip. Per block: pair indices (i,j)
// computed once from act[]; per K-step each thread loads 2x32B of att rows i,j,
// packs 16 bf16, ds_write_b128 (per-lane scatter -> swizzle applied at write).
// Schedule: ONE __syncthreads per K-step (was 2 barriers + manual vmcnt):
//   [issue att(kt+1) + A-gload(kt+1)] -> MFMA(kt) hides them -> pack B(kt+1) -> sync.
// bf16 rounding + MFMA order identical to the old path -> bit-identical output.
// A-panel stays materialized (A1p, reused 66x). grid (9,136); x==8: logits gemv.
__global__ __launch_bounds__(512, 4) void gemm_fused(
        const __bf16* __restrict__ A1p, const float* __restrict__ att,
        const int* __restrict__ actg,
        const __bf16* __restrict__ K2w, const float* __restrict__ c1b,
        const int* __restrict__ counts,
        float* __restrict__ Q, float* __restrict__ Qs,
        const float* __restrict__ hid, const float* __restrict__ cls_w,
        const float* __restrict__ cls_b, float* __restrict__ logits) {
    int x = blockIdx.x, y = blockIdx.y;
    int tid = threadIdx.x, wave = tid >> 6, lane = tid & 63;

    if (x == 8) {
#pragma unroll
        for (int rr = 0; rr < 2; rr++) {
            int o = y * 16 + wave * 2 + rr;
            if (o >= 2000) break;
            const float* row = cls_w + (size_t)o * CH;
            float s = 0.f;
            for (int c = lane; c < CH; c += 64) s += hid[c] * row[c];
            for (int d = 32; d; d >>= 1) s += __shfl_down(s, d);
            if (lane == 0) logits[o] = s + cls_b[o];
        }
        return;
    }

    int A = counts[0];
    int P = counts[1]; if (P > PCAP) P = PCAP;   // same clamp as old FEATP
    int Ppad = counts[2];
    int ntp = Ppad >> 7;                 // 128-col pair tiles
    int ntiles = ntp + 2;                // + 2 single tiles (256 rows)
    int c_rt = (ntiles + 7) >> 3;
    int g = (x + y) & 7;                 // XCD id under linear id (x + 9y) % 8
    int nbl = y >> 3, mb = y & 7;
    if (nbl >= c_rt) return;
    int nb = g * c_rt + nbl;
    if (nb >= ntiles) return;
    bool sing = (nb >= ntp);

    __shared__ __align__(16) char smemraw[65536];
    __shared__ int pairs[256];
#define ASP(bsel) ((__bf16(*)[64])(smemraw + (bsel) * 16384))
#define BSP(bsel) ((__bf16(*)[64])(smemraw + 32768 + (bsel) * 16384))
#define HTL ((__bf16(*)[136])(smemraw))
#define K2L ((__bf16(*)[136])(smemraw + 34816))

    // ---- pair setup (once per block): row n -> (i, j); j=-2 for singles (b=0),
    // i=-1 for pad rows (a=b=0) ----
    if (tid < 128) {
        int i = -1, j = -1;
        if (sing) {
            i = (nb - ntp) * 128 + tid;        // att row, < 256
            j = -2;
        } else {
            int n = nb * 128 + tid;
            if (n < P && A > 0) {
                float fA = (float)(2 * A + 1);
                float disc = fmaxf(fA * fA - 8.0f * (float)n, 0.0f);
                int r = (int)floorf((fA - sqrtf(disc)) * 0.5f);
                r = min(A - 1, max(0, r));
                while (r > 0 && offA(r, A) > n) --r;
                while (r < A - 1 && offA(r + 1, A) <= n) ++r;
                i = actg[r]; j = actg[r + (n - offA(r, A))];
            }
        }
        pairs[2 * tid] = i; pairs[2 * tid + 1] = j;
    }

    // A staging (unchanged: pre-swizzled source, linear LDS dest)
    int lanerow = lane >> 3;
    int swchunk = ((lane & 7) ^ lanerow) * 8;
    const __bf16* srcA = A1p + (size_t)(mb * 128 + wave * 16 + lanerow) * KI + swchunk;

    __syncthreads();

    int myrow = tid >> 2, q4 = tid & 3;          // B: 128 rows x 4 quarter-slices
    int pi = pairs[2 * myrow], pj = pairs[2 * myrow + 1];
    const float* attI = att + (size_t)max(pi, 0) * CH;
    const float* attJ = att + (size_t)max(pj, 0) * CH;
    bool vi = pi >= 0, vj = pj >= 0;
    int sw0 = ((2 * q4) ^ (myrow & 7)) * 8;      // write-side swizzle == read-side XOR
    int sw1 = ((2 * q4 + 1) ^ (myrow & 7)) * 8;

    f4v acc[4][2] = {};
    int row16 = lane & 15, quad = lane >> 4;
    int wx = wave & 3, wy = wave >> 2;   // wave tile: rows wy*64+mt*16, cols wx*32+nt*16
    float4 zero4 = {0.f, 0.f, 0.f, 0.f};
    float4 pA0, pA1, pB0, pB1;

#define STAGEA(kt, bsel)                                                          \
    {                                                                             \
        const __bf16* sA = srcA + (kt) * 64;                                      \
        _Pragma("unroll")                                                         \
        for (int q = 0; q < 2; q++) {                                             \
            __builtin_amdgcn_global_load_lds(                                     \
                (const __attribute__((address_space(1))) void*)(sA + (size_t)q * 8 * KI), \
                (__attribute__((address_space(3))) void*)&ASP(bsel)[wave * 16 + q * 8][0], 16, 0, 0); \
        }                                                                         \
    }

#define LOADATT(kt)                                                               \
    {                                                                             \
        int cb = (kt) * 32 + q4 * 8;                                              \
        pA0 = vi ? *(const float4*)&attI[cb]     : zero4;                         \
        pA1 = vi ? *(const float4*)&attI[cb + 4] : zero4;                         \
        pB0 = vj ? *(const float4*)&attJ[cb]     : zero4;                         \
        pB1 = vj ? *(const float4*)&attJ[cb + 4] : zero4;                         \
    }

#define PACKB(bsel)                                                               \
    {                                                                             \
        bf16x8 v0, v1;                                                            \
        v0[0] = (__bf16)fabsf(pA0.x - pB0.x); v0[1] = (__bf16)(pA0.x * pB0.x);    \
        v0[2] = (__bf16)fabsf(pA0.y - pB0.y); v0[3] = (__bf16)(pA0.y * pB0.y);    \
        v0[4] = (__bf16)fabsf(pA0.z - pB0.z); v0[5] = (__bf16)(pA0.z * pB0.z);    \
        v0[6] = (__bf16)fabsf(pA0.w - pB0.w); v0[7] = (__bf16)(pA0.w * pB0.w);    \
        v1[0] = (__bf16)fabsf(pA1.x - pB1.x); v1[1] = (__bf16)(pA1.x * pB1.x);    \
        v1[2] = (__bf16)fabsf(pA1.y - pB1.y); v1[3] = (__bf16)(pA1.y * pB1.y);    \
        v1[4] = (__bf16)fabsf(pA1.z - pB1.z); v1[5] = (__bf16)(pA1.z * pB1.z);    \
        v1[6] = (__bf16)fabsf(pA1.w - pB1.w); v1[7] = (__bf16)(pA1.w * pB1.w);    \
        *(bf16x8*)&BSP(bsel)[myrow][sw0] = v0;                                    \
        *(bf16x8*)&BSP(bsel)[myrow][sw1] = v1;                                    \
    }

    LOADATT(0);
    STAGEA(0, 0);
    PACKB(0);
    __syncthreads();                      // A(0) in LDS, B(0) written

    for (int kt = 0; kt < KIT; ++kt) {
        int cur = kt & 1;
        if (kt + 1 < KIT) {
            LOADATT(kt + 1);              // issue early; MFMA hides latency
            STAGEA(kt + 1, cur ^ 1);
        }
#pragma unroll
        for (int ks = 0; ks < 2; ks++) {
            bf16x8 a[4], b[2];
            int col = ((ks * 4 + quad) ^ (row16 & 7)) * 8;
#pragma unroll
            for (int mt = 0; mt < 4; mt++)
                a[mt] = *(const bf16x8*)&ASP(cur)[wy * 64 + mt * 16 + row16][col];
#pragma unroll
            for (int nt = 0; nt < 2; nt++)
                b[nt] = *(const bf16x8*)&BSP(cur)[wx * 32 + nt * 16 + row16][col];
#pragma unroll
            for (int mt = 0; mt < 4; mt++)
#pragma unroll
                for (int nt = 0; nt < 2; nt++)
                    acc[mt][nt] = __builtin_amdgcn_mfma_f32_16x16x32_bf16(a[mt], b[nt], acc[mt][nt], 0, 0, 0);
        }
        if (kt + 1 < KIT) PACKB(cur ^ 1);
        __syncthreads();                  // drains gload_lds + ds_write, one barrier/step
    }
#undef STAGEA
#undef LOADATT
#undef PACKB

    // ---- phase 2: K2 tile + relu(h) tile in LDS, contract 128 local o's ----
#pragma unroll
    for (int it = 0; it < 2; it++) {
        int gid = it * 512 + tid;                  // 1024 = 64 rows x 16 chunks
        int trow = gid >> 4, oc = (gid & 15) * 8;
        bf16x8 kv = *(const bf16x8*)&K2w[(size_t)trow * CH + mb * 128 + oc];
        *(bf16x8*)&K2L[trow][oc] = kv;
    }
#pragma unroll
    for (int mt = 0; mt < 4; mt++) {
        int ol = wy * 64 + mt * 16 + quad * 4;
        float4 bv = *(const float4*)&c1b[mb * 128 + ol];
#pragma unroll
        for (int nt = 0; nt < 2; nt++) {
            int n = wx * 32 + nt * 16 + row16;
            bf16x4 pk;
            pk[0] = (__bf16)fmaxf(acc[mt][nt][0] + bv.x, 0.f);
            pk[1] = (__bf16)fmaxf(acc[mt][nt][1] + bv.y, 0.f);
            pk[2] = (__bf16)fmaxf(acc[mt][nt][2] + bv.z, 0.f);
            pk[3] = (__bf16)fmaxf(acc[mt][nt][3] + bv.w, 0.f);
            *(bf16x4*)&HTL[n][ol] = pk;
        }
    }
    __syncthreads();

    // waves: tq = wave&3 covers t rows tq*16+row16; nhalf = wave>>2 covers n cols nhalf*64
    int tq = wave & 3, nhalf = wave >> 2;
    f4v acc2[4] = {};
#pragma unroll
    for (int ko = 0; ko < 4; ko++) {
        bf16x8 af = *(const bf16x8*)&K2L[tq * 16 + row16][ko * 32 + quad * 8];
#pragma unroll
        for (int nt = 0; nt < 4; nt++) {
            bf16x8 bf_ = *(const bf16x8*)&HTL[nhalf * 64 + nt * 16 + row16][ko * 32 + quad * 8];
            acc2[nt] = __builtin_amdgcn_mfma_f32_16x16x32_bf16(af, bf_, acc2[nt], 0, 0, 0);
        }
    }

    float* Qdst = sing ? Qs : Q;
    int ldq = sing ? 256 : LDQ;
    int nbase = sing ? (nb - ntp) * 128 : nb * 128;
    int t0 = tq * 16 + quad * 4;
#pragma unroll
    for (int nt = 0; nt < 4; nt++) {
        int n = nbase + nhalf * 64 + nt * 16 + row16;
#pragma unroll
        for (int r = 0; r < 4; r++)
            if (t0 + r < 49) atomicAdd(&Qdst[(size_t)(t0 + r) * ldq + n], acc2[nt][r]);
    }
#undef ASP
#undef BSP
#undef HTL
#undef K2L
}

// ---------------- output: 1024 threads, 4-way tap split, branchless gather -----------
__global__ __launch_bounds__(1024) void k_out(
                      const float* __restrict__ Q, const float* __restrict__ Qs,
                      const float* __restrict__ Qc, const int* __restrict__ rank,
                      const int* __restrict__ counts, const float* b2,
                      float* __restrict__ outmaps) {
    __shared__ int rankL[256];
    __shared__ float part[1024];
    int tt_ = threadIdx.x, i = blockIdx.x;
    int t = tt_ & 255;
    int quarter = tt_ >> 8;
    if (tt_ < 256) rankL[tt_] = rank[tt_];
    __syncthreads();
    int A = counts[0];
    int j = t;

    int qc_[7], rq_[7], oq_[7];
    bool vq_[7];
#pragma unroll
    for (int dj = 0; dj < 7; dj++) {
        int q = j + dj - 3;
        vq_[dj] = ((unsigned)q <= 255u);
        int qc = min(255, max(0, q));
        qc_[dj] = qc;
        int r = rankL[qc];
        rq_[dj] = r;
        oq_[dj] = offA(max(r, 0), A);
    }

    float acc = (quarter == 0) ? b2[0] : 0.f;
#pragma unroll
    for (int di = 0; di < 7; di++) {
        int p = i + di - 3;                      // block-uniform
        bool vp = ((unsigned)p <= 255u);
        int pc = min(255, max(0, p));
        int rp = rankL[pc];
        int op = offA(max(rp, 0), A);
#pragma unroll
        for (int dj = 0; dj < 7; dj++) {
            int tt = di * 7 + dj;
            if ((tt & 3) != quarter) continue;   // compile-time tt, wave-uniform quarter
            int qc = qc_[dj];
            bool pfirst = (pc <= qc);
            int a  = pfirst ? pc : qc;
            int bb = pfirst ? qc : pc;
            int ra = pfirst ? rp : rq_[dj];
            int rb = pfirst ? rq_[dj] : rp;
            int oa = pfirst ? op : oq_[dj];
            const float* s1 = (rb >= 0) ? (Q + (size_t)tt * LDQ + (oa + rb - ra))
                                        : (Qs + tt * 256 + a);
            const float* s0 = (rb >= 0) ? (Qs + tt * 256 + bb)
                                        : (Qc + tt);
            const float* sp = (ra >= 0) ? s1 : s0;
            float val = *sp;
            acc = (vp && vq_[dj]) ? (acc + val) : acc;
        }
    }
    part[tt_] = acc;
    __syncthreads();
    if (tt_ < 256) {
        float s = (part[tt_] + part[tt_ + 256]) + (part[tt_ + 512] + part[tt_ + 768]);
        outmaps[i * 256 + j] = 1.0f / (1.0f + expf(-s));
    }
}

// ---------------- launch ----------------

extern "C" void kernel_launch(void* const* d_in, const int* in_sizes, int n_in,
                              void* d_out, int out_size, void* d_ws, size_t ws_size,
                              hipStream_t stream) {
    const float* att    = (const float*)d_in[0];
    const float* pooled = (const float*)d_in[1];
    const int*   am     = (const int*)d_in[2];
    const float* lin1_w = (const float*)d_in[3];
    const float* lin1_b = (const float*)d_in[4];
    const float* cls_w  = (const float*)d_in[5];
    const float* cls_b  = (const float*)d_in[6];
    const float* c1w    = (const float*)d_in[7];
    const float* c1b    = (const float*)d_in[8];
    const float* c2w    = (const float*)d_in[9];
    const float* c2b    = (const float*)d_in[10];
    float* out = (float*)d_out;
    char*  ws  = (char*)d_ws;

    // workspace (~7.6 MB — featT eliminated)
    __bf16* A1p  = (__bf16*)(ws);                 // 1024*2048*2 = 4,194,304
    __bf16* K2w  = (__bf16*)(ws + 4194304);       // 64*1024*2   =   131,072
    float*  Q    = (float*) (ws + 4325376);       // 49*16384*4  = 3,211,264
    float*  Qs   = (float*) (ws + 7536640);       // 49*256*4    =    50,176  (contiguous with Q)
    float*  Qc   = (float*) (ws + 7586816);       // 49*4 (pad 256)
    int*    rank = (int*)   (ws + 7587072);       // 256*4 (pad 1024)
    float*  hid  = (float*) (ws + 7588096);       // 1024*4
    int*    counts=(int*)   (ws + 7592192);       // 16*4 (pad to 768)
    int*    actg = (int*)   (ws + 7592960);       // 256*4

    k_prep<<<PB_TOTAL, 256, 0, stream>>>(att, am, c1w, c2w, c1b, pooled, lin1_w, lin1_b,
                                         rank, counts, actg, A1p, K2w, Qc, Q, hid);

    gemm_fused<<<dim3(9, 136), 512, 0, stream>>>(A1p, att, actg, K2w, c1b, counts, Q, Qs,
                                                 hid, cls_w, cls_b, out);

    k_out<<<256, 1024, 0, stream>>>(Q, Qs, Qc, rank, counts, c2b, out + 2000);
}

// Round 16
// 151.163 us; speedup vs baseline: 1.7304x; 1.7304x over previous
//
#include <hip/hip_runtime.h>

typedef float  f4v    __attribute__((ext_vector_type(4)));
typedef __bf16 bf16x8 __attribute__((ext_vector_type(8)));
typedef __bf16 bf16x4 __attribute__((ext_vector_type(4)));

#define PCAP  16384   // max pair rows (clamp bound; actual A~127 -> Ppad 8192)
#define LDQ   16384
#define CH    1024
#define KI    2048    // interleaved K (diff/mul alternating)
#define KIT   32      // K iterations (BK=64)

__device__ __forceinline__ int offA(int r, int A) { return r * A - ((r * (r - 1)) >> 1); }

// ballot-scan of mask -> act[], A
__device__ __forceinline__ int mask_scan(const int* am, int t, int* act,
                                         unsigned long long* wm, int* wred) {
    int wave = t >> 6, lane = t & 63;
    int a = am[t];
    int sv = a;
#pragma unroll
    for (int d = 32; d; d >>= 1) sv += __shfl_down(sv, d);
    if (lane == 0) wred[wave] = sv;
    __syncthreads();
    int s = wred[0] + wred[1] + wred[2] + wred[3];
    int keep = (t != 0 && t != s && a != 0) ? 1 : 0;
    unsigned long long bm = __ballot(keep);
    if (lane == 0) wm[wave] = bm;
    __syncthreads();
    int base = 0, A = 0;
#pragma unroll
    for (int w = 0; w < 4; w++) {
        int pc = __popcll(wm[w]);
        if (w < wave) base += pc;
        A += pc;
    }
    if (keep) act[base + __popcll(bm & ((1ull << lane) - 1ull))] = t;
    __syncthreads();
    return A;
}

// ---------------- prep kernel (featT generation fused into gemm) ----------------
#define PB_CVTA   0       // 512: A1p interleaved bf16 conv of conv1_w
#define PB_K2     512     // 256: K2w[64][1024]
#define PB_QCONST 768     // 49
#define PB_ZERO   817     // 797: zero Q + Qs (contiguous)
#define PB_SCAN   1614    // 1: rank/counts/act export
#define PB_HID    1615    // 256: hid gemv
#define PB_TOTAL  1871

__global__ void k_prep(const float* __restrict__ att, const int* __restrict__ am,
                       const float* __restrict__ c1w, const float* __restrict__ c2w,
                       const float* __restrict__ c1b,
                       const float* __restrict__ pooled, const float* __restrict__ lin1_w,
                       const float* __restrict__ lin1_b,
                       int* rank, int* counts, int* actg, __bf16* A1p, __bf16* K2w,
                       float* Qc, float* Qzero, float* hid) {
    int b = blockIdx.x, t = threadIdx.x;

    if (b < PB_K2) {
        int gid = b * 256 + t;              // 131072
        int o = gid >> 7, cw = (gid & 127) * 8;
        const float* wd = &c1w[o * 2048 + cw];
        const float* wmu = &c1w[o * 2048 + 1024 + cw];
        float4 d0 = *(const float4*)wd,  d1 = *(const float4*)(wd + 4);
        float4 m0 = *(const float4*)wmu, m1 = *(const float4*)(wmu + 4);
        bf16x8 v0, v1;
        v0[0] = (__bf16)d0.x; v0[1] = (__bf16)m0.x; v0[2] = (__bf16)d0.y; v0[3] = (__bf16)m0.y;
        v0[4] = (__bf16)d0.z; v0[5] = (__bf16)m0.z; v0[6] = (__bf16)d0.w; v0[7] = (__bf16)m0.w;
        v1[0] = (__bf16)d1.x; v1[1] = (__bf16)m1.x; v1[2] = (__bf16)d1.y; v1[3] = (__bf16)m1.y;
        v1[4] = (__bf16)d1.z; v1[5] = (__bf16)m1.z; v1[6] = (__bf16)d1.w; v1[7] = (__bf16)m1.w;
        *(bf16x8*)&A1p[o * 2048 + 2 * cw] = v0;
        *(bf16x8*)&A1p[o * 2048 + 2 * cw + 8] = v1;
    } else if (b < PB_QCONST) {
        int e = (b - PB_K2) * 256 + t;      // 65536 = 64*1024
        int trow = e >> 10, o = e & 1023;
        K2w[e] = (trow < 49) ? (__bf16)c2w[o * 49 + trow] : (__bf16)0.0f;
    } else if (b < PB_ZERO) {
        __shared__ float sh[256];
        int tap = b - PB_K2 - 256 + 0;      // unused path guard
        tap = b - PB_QCONST;
        float s = 0.f;
        for (int o = t; o < CH; o += 256) s += c2w[o * 49 + tap] * fmaxf(c1b[o], 0.f);
        sh[t] = s; __syncthreads();
        for (int d = 128; d; d >>= 1) { if (t < d) sh[t] += sh[t + d]; __syncthreads(); }
        if (t == 0) Qc[tap] = sh[0];
    } else if (b < PB_SCAN) {
        int idx = (b - PB_ZERO) * 256 + t;  // 203840 float4 = Q(49*16384) + Qs(49*256)
        if (idx < 203840) {
            float4 zv = {0.f, 0.f, 0.f, 0.f};
            ((float4*)Qzero)[idx] = zv;
        }
    } else if (b == PB_SCAN) {
        __shared__ int act[256];
        __shared__ unsigned long long wm[4];
        __shared__ int wred[4];
        int A = mask_scan(am, t, act, wm, wred);
        int wave = t >> 6, lane = t & 63;
        int s = wred[0] + wred[1] + wred[2] + wred[3];
        int keep = (t != 0 && t != s && am[t] != 0) ? 1 : 0;
        int base = 0;
#pragma unroll
        for (int w = 0; w < 4; w++) if (w < wave) base += __popcll(wm[w]);
        unsigned long long bm = wm[wave];
        rank[t] = keep ? (base + __popcll(bm & ((1ull << lane) - 1ull))) : -1;
        actg[t] = (t < A) ? act[t] : 0;     // export kept indices for fused gemm
        if (t == 0) {
            int P = (A * (A + 1)) >> 1;
            int Pp = ((P + 127) >> 7) << 7;
            if (Pp > PCAP) Pp = PCAP;
            counts[0] = A; counts[1] = P; counts[2] = Pp;
        }
    } else {
        int o = (b - PB_HID) * 4 + (t >> 6);
        int lane = t & 63;
        const float* row = lin1_w + (size_t)o * CH;
        float s = 0.f;
        for (int c = lane; c < CH; c += 64) s += pooled[c] * row[c];
        for (int d = 32; d; d >>= 1) s += __shfl_down(s, d);
        if (lane == 0) hid[o] = s + lin1_b[o];
    }
}

// ---------------- GEMM, FUSED B-gen, R2-style counted-vmcnt pipeline -----------------
// R15 failure analysis: one __syncthreads/K-step drained vmcnt(0) -> att gather latency
// fully exposed every iter (MfmaUtil 7%, 170us). Fix: 2-deep att register pipeline +
// counted waits, mirroring R2's proven pattern:
//   iter kt: STAGEA(kt+1) [2 gloads], LOADATT(kt+2) [4 loads, unconditional],
//            MFMA(kt), vmcnt(6)->PACKB(kt+1) [att(kt+1) issued a FULL iter ago],
//            vmcnt(4)+lgkm(0)+barrier  [A(kt+1) drained; att(kt+2) stays IN FLIGHT].
// Even/odd unrolled with NAMED reg sets (no runtime-indexed arrays); loads are
// unconditional (clamped row-0 addr) so per-wave vmcnt issue counts are deterministic;
// pad/single validity applied as value-selects in PACKB. Tail (kt=30,31) peeled with
// exact waits vmcnt(2)/vmcnt(0). Math/rounding identical -> bit-identical output.
__global__ __launch_bounds__(512) void gemm_fused(
        const __bf16* __restrict__ A1p, const float* __restrict__ att,
        const int* __restrict__ actg,
        const __bf16* __restrict__ K2w, const float* __restrict__ c1b,
        const int* __restrict__ counts,
        float* __restrict__ Q, float* __restrict__ Qs,
        const float* __restrict__ hid, const float* __restrict__ cls_w,
        const float* __restrict__ cls_b, float* __restrict__ logits) {
    int x = blockIdx.x, y = blockIdx.y;
    int tid = threadIdx.x, wave = tid >> 6, lane = tid & 63;

    if (x == 8) {
#pragma unroll
        for (int rr = 0; rr < 2; rr++) {
            int o = y * 16 + wave * 2 + rr;
            if (o >= 2000) break;
            const float* row = cls_w + (size_t)o * CH;
            float s = 0.f;
            for (int c = lane; c < CH; c += 64) s += hid[c] * row[c];
            for (int d = 32; d; d >>= 1) s += __shfl_down(s, d);
            if (lane == 0) logits[o] = s + cls_b[o];
        }
        return;
    }

    int A = counts[0];
    int P = counts[1]; if (P > PCAP) P = PCAP;
    int Ppad = counts[2];
    int ntp = Ppad >> 7;                 // 128-col pair tiles
    int ntiles = ntp + 2;                // + 2 single tiles (256 rows)
    int c_rt = (ntiles + 7) >> 3;
    int g = (x + y) & 7;                 // XCD id under linear id (x + 9y) % 8
    int nbl = y >> 3, mb = y & 7;
    if (nbl >= c_rt) return;
    int nb = g * c_rt + nbl;
    if (nb >= ntiles) return;
    bool sing = (nb >= ntp);

    __shared__ __align__(16) char smemraw[65536];
    __shared__ int pairs[256];
#define ASP(bsel) ((__bf16(*)[64])(smemraw + (bsel) * 16384))
#define BSP(bsel) ((__bf16(*)[64])(smemraw + 32768 + (bsel) * 16384))
#define HTL ((__bf16(*)[136])(smemraw))
#define K2L ((__bf16(*)[136])(smemraw + 34816))

    // ---- pair setup (once per block): row n -> (i, j); j=-2 for singles,
    // i=-1 for pad rows ----
    if (tid < 128) {
        int i = -1, j = -1;
        if (sing) {
            i = (nb - ntp) * 128 + tid;
            j = -2;
        } else {
            int n = nb * 128 + tid;
            if (n < P && A > 0) {
                float fA = (float)(2 * A + 1);
                float disc = fmaxf(fA * fA - 8.0f * (float)n, 0.0f);
                int r = (int)floorf((fA - sqrtf(disc)) * 0.5f);
                r = min(A - 1, max(0, r));
                while (r > 0 && offA(r, A) > n) --r;
                while (r < A - 1 && offA(r + 1, A) <= n) ++r;
                i = actg[r]; j = actg[r + (n - offA(r, A))];
            }
        }
        pairs[2 * tid] = i; pairs[2 * tid + 1] = j;
    }

    // A staging (pre-swizzled source, linear LDS dest)
    int lanerow = lane >> 3;
    int swchunk = ((lane & 7) ^ lanerow) * 8;
    const __bf16* srcA = A1p + (size_t)(mb * 128 + wave * 16 + lanerow) * KI + swchunk;

    __syncthreads();

    int myrow = tid >> 2, q4 = tid & 3;          // B: 128 rows x 4 quarter-slices
    int pi = pairs[2 * myrow], pj = pairs[2 * myrow + 1];
    const float* attI = att + (size_t)max(pi, 0) * CH;   // clamped: loads always valid
    const float* attJ = att + (size_t)max(pj, 0) * CH;
    bool vi = pi >= 0, vj = pj >= 0;
    int sw0 = ((2 * q4) ^ (myrow & 7)) * 8;      // write-side swizzle == read-side XOR
    int sw1 = ((2 * q4 + 1) ^ (myrow & 7)) * 8;

    f4v acc[4][2] = {};
    int row16 = lane & 15, quad = lane >> 4;
    int wx = wave & 3, wy = wave >> 2;
    float4 zero4 = {0.f, 0.f, 0.f, 0.f};
    float4 eA0, eA1, eB0, eB1, oA0, oA1, oB0, oB1;   // named 2-deep att reg sets

#define STAGEA(kt, bsel)                                                          \
    {                                                                             \
        const __bf16* sA = srcA + (kt) * 64;                                      \
        _Pragma("unroll")                                                         \
        for (int q = 0; q < 2; q++) {                                             \
            __builtin_amdgcn_global_load_lds(                                     \
                (const __attribute__((address_space(1))) void*)(sA + (size_t)q * 8 * KI), \
                (__attribute__((address_space(3))) void*)&ASP(bsel)[wave * 16 + q * 8][0], 16, 0, 0); \
        }                                                                         \
    }

#define LOADATT(kt, rA0, rA1, rB0, rB1)                                           \
    {                                                                             \
        int cb = (kt) * 32 + q4 * 8;                                              \
        rA0 = *(const float4*)&attI[cb];                                          \
        rA1 = *(const float4*)&attI[cb + 4];                                      \
        rB0 = *(const float4*)&attJ[cb];                                          \
        rB1 = *(const float4*)&attJ[cb + 4];                                      \
    }

#define PACKB(bsel, rA0, rA1, rB0, rB1)                                           \
    {                                                                             \
        float4 a0 = vi ? rA0 : zero4, a1 = vi ? rA1 : zero4;                      \
        float4 b0 = vj ? rB0 : zero4, b1 = vj ? rB1 : zero4;                      \
        bf16x8 v0, v1;                                                            \
        v0[0] = (__bf16)fabsf(a0.x - b0.x); v0[1] = (__bf16)(a0.x * b0.x);        \
        v0[2] = (__bf16)fabsf(a0.y - b0.y); v0[3] = (__bf16)(a0.y * b0.y);        \
        v0[4] = (__bf16)fabsf(a0.z - b0.z); v0[5] = (__bf16)(a0.z * b0.z);        \
        v0[6] = (__bf16)fabsf(a0.w - b0.w); v0[7] = (__bf16)(a0.w * b0.w);        \
        v1[0] = (__bf16)fabsf(a1.x - b1.x); v1[1] = (__bf16)(a1.x * b1.x);        \
        v1[2] = (__bf16)fabsf(a1.y - b1.y); v1[3] = (__bf16)(a1.y * b1.y);        \
        v1[4] = (__bf16)fabsf(a1.z - b1.z); v1[5] = (__bf16)(a1.z * b1.z);        \
        v1[6] = (__bf16)fabsf(a1.w - b1.w); v1[7] = (__bf16)(a1.w * b1.w);        \
        *(bf16x8*)&BSP(bsel)[myrow][sw0] = v0;                                    \
        *(bf16x8*)&BSP(bsel)[myrow][sw1] = v1;                                    \
    }

#define MFMABODY(bsel)                                                            \
    _Pragma("unroll")                                                             \
    for (int ks = 0; ks < 2; ks++) {                                              \
        bf16x8 a[4], b[2];                                                        \
        int col = ((ks * 4 + quad) ^ (row16 & 7)) * 8;                            \
        _Pragma("unroll")                                                         \
        for (int mt = 0; mt < 4; mt++)                                            \
            a[mt] = *(const bf16x8*)&ASP(bsel)[wy * 64 + mt * 16 + row16][col];   \
        _Pragma("unroll")                                                         \
        for (int nt = 0; nt < 2; nt++)                                            \
            b[nt] = *(const bf16x8*)&BSP(bsel)[wx * 32 + nt * 16 + row16][col];   \
        _Pragma("unroll")                                                         \
        for (int mt = 0; mt < 4; mt++)                                            \
            _Pragma("unroll")                                                     \
            for (int nt = 0; nt < 2; nt++)                                        \
                acc[mt][nt] = __builtin_amdgcn_mfma_f32_16x16x32_bf16(a[mt], b[nt], acc[mt][nt], 0, 0, 0); \
    }

    // prologue: queue = [A(0)x2, attE(0)x4, attO(1)x4]
    STAGEA(0, 0);
    LOADATT(0, eA0, eA1, eB0, eB1);
    LOADATT(1, oA0, oA1, oB0, oB1);
    __builtin_amdgcn_s_waitcnt(0xF74);   // drain A(0)+attE(0); attO(1)x4 in flight
    PACKB(0, eA0, eA1, eB0, eB1);
    __builtin_amdgcn_s_waitcnt(0x074);   // lgkm(0) for ds_writes (vmcnt<=4 holds)
    __builtin_amdgcn_s_barrier();

    // main loop: pairs (kt, kt+1), kt = 0..28 — all pipeline slots full
    for (int kt = 0; kt < 30; kt += 2) {
        // even tile kt in buf0; entering in-flight: attO(kt+1)x4
        STAGEA(kt + 1, 1);                        // +A(kt+1)x2
        LOADATT(kt + 2, eA0, eA1, eB0, eB1);      // +attE(kt+2)x4
        MFMABODY(0);
        __builtin_amdgcn_s_waitcnt(0xF76);        // drain attO(kt+1)
        PACKB(1, oA0, oA1, oB0, oB1);
        __builtin_amdgcn_s_waitcnt(0x074);        // drain A(kt+1), lgkm0; keep attE(kt+2)
        __builtin_amdgcn_s_barrier();
        // odd tile kt+1 in buf1; entering in-flight: attE(kt+2)x4
        STAGEA(kt + 2, 0);                        // +A(kt+2)x2
        LOADATT(kt + 3, oA0, oA1, oB0, oB1);      // +attO(kt+3)x4
        MFMABODY(1);
        __builtin_amdgcn_s_waitcnt(0xF76);        // drain attE(kt+2)
        PACKB(0, eA0, eA1, eB0, eB1);
        __builtin_amdgcn_s_waitcnt(0x074);        // drain A(kt+2), lgkm0; keep attO(kt+3)
        __builtin_amdgcn_s_barrier();
    }
    // tail kt=30: in-flight attO(31)x4
    STAGEA(31, 1);                                // +A(31)x2
    MFMABODY(0);
    __builtin_amdgcn_s_waitcnt(0xF72);            // drain attO(31) (A(31)x2 newer)
    PACKB(1, oA0, oA1, oB0, oB1);
    __builtin_amdgcn_s_waitcnt(0x070);            // drain A(31), lgkm0
    __builtin_amdgcn_s_barrier();
    // tail kt=31
    MFMABODY(1);
    __syncthreads();
#undef STAGEA
#undef LOADATT
#undef PACKB
#undef MFMABODY

    // ---- phase 2: K2 tile + relu(h) tile in LDS, contract 128 local o's ----
#pragma unroll
    for (int it = 0; it < 2; it++) {
        int gid = it * 512 + tid;                  // 1024 = 64 rows x 16 chunks
        int trow = gid >> 4, oc = (gid & 15) * 8;
        bf16x8 kv = *(const bf16x8*)&K2w[(size_t)trow * CH + mb * 128 + oc];
        *(bf16x8*)&K2L[trow][oc] = kv;
    }
#pragma unroll
    for (int mt = 0; mt < 4; mt++) {
        int ol = wy * 64 + mt * 16 + quad * 4;
        float4 bv = *(const float4*)&c1b[mb * 128 + ol];
#pragma unroll
        for (int nt = 0; nt < 2; nt++) {
            int n = wx * 32 + nt * 16 + row16;
            bf16x4 pk;
            pk[0] = (__bf16)fmaxf(acc[mt][nt][0] + bv.x, 0.f);
            pk[1] = (__bf16)fmaxf(acc[mt][nt][1] + bv.y, 0.f);
            pk[2] = (__bf16)fmaxf(acc[mt][nt][2] + bv.z, 0.f);
            pk[3] = (__bf16)fmaxf(acc[mt][nt][3] + bv.w, 0.f);
            *(bf16x4*)&HTL[n][ol] = pk;
        }
    }
    __syncthreads();

    int tq = wave & 3, nhalf = wave >> 2;
    f4v acc2[4] = {};
#pragma unroll
    for (int ko = 0; ko < 4; ko++) {
        bf16x8 af = *(const bf16x8*)&K2L[tq * 16 + row16][ko * 32 + quad * 8];
#pragma unroll
        for (int nt = 0; nt < 4; nt++) {
            bf16x8 bf_ = *(const bf16x8*)&HTL[nhalf * 64 + nt * 16 + row16][ko * 32 + quad * 8];
            acc2[nt] = __builtin_amdgcn_mfma_f32_16x16x32_bf16(af, bf_, acc2[nt], 0, 0, 0);
        }
    }

    float* Qdst = sing ? Qs : Q;
    int ldq = sing ? 256 : LDQ;
    int nbase = sing ? (nb - ntp) * 128 : nb * 128;
    int t0 = tq * 16 + quad * 4;
#pragma unroll
    for (int nt = 0; nt < 4; nt++) {
        int n = nbase + nhalf * 64 + nt * 16 + row16;
#pragma unroll
        for (int r = 0; r < 4; r++)
            if (t0 + r < 49) atomicAdd(&Qdst[(size_t)(t0 + r) * ldq + n], acc2[nt][r]);
    }
#undef ASP
#undef BSP
#undef HTL
#undef K2L
}

// ---------------- output: 1024 threads, 4-way tap split, branchless gather -----------
__global__ __launch_bounds__(1024) void k_out(
                      const float* __restrict__ Q, const float* __restrict__ Qs,
                      const float* __restrict__ Qc, const int* __restrict__ rank,
                      const int* __restrict__ counts, const float* b2,
                      float* __restrict__ outmaps) {
    __shared__ int rankL[256];
    __shared__ float part[1024];
    int tt_ = threadIdx.x, i = blockIdx.x;
    int t = tt_ & 255;
    int quarter = tt_ >> 8;
    if (tt_ < 256) rankL[tt_] = rank[tt_];
    __syncthreads();
    int A = counts[0];
    int j = t;

    int qc_[7], rq_[7], oq_[7];
    bool vq_[7];
#pragma unroll
    for (int dj = 0; dj < 7; dj++) {
        int q = j + dj - 3;
        vq_[dj] = ((unsigned)q <= 255u);
        int qc = min(255, max(0, q));
        qc_[dj] = qc;
        int r = rankL[qc];
        rq_[dj] = r;
        oq_[dj] = offA(max(r, 0), A);
    }

    float acc = (quarter == 0) ? b2[0] : 0.f;
#pragma unroll
    for (int di = 0; di < 7; di++) {
        int p = i + di - 3;                      // block-uniform
        bool vp = ((unsigned)p <= 255u);
        int pc = min(255, max(0, p));
        int rp = rankL[pc];
        int op = offA(max(rp, 0), A);
#pragma unroll
        for (int dj = 0; dj < 7; dj++) {
            int tt = di * 7 + dj;
            if ((tt & 3) != quarter) continue;   // compile-time tt, wave-uniform quarter
            int qc = qc_[dj];
            bool pfirst = (pc <= qc);
            int a  = pfirst ? pc : qc;
            int bb = pfirst ? qc : pc;
            int ra = pfirst ? rp : rq_[dj];
            int rb = pfirst ? rq_[dj] : rp;
            int oa = pfirst ? op : oq_[dj];
            const float* s1 = (rb >= 0) ? (Q + (size_t)tt * LDQ + (oa + rb - ra))
                                        : (Qs + tt * 256 + a);
            const float* s0 = (rb >= 0) ? (Qs + tt * 256 + bb)
                                        : (Qc + tt);
            const float* sp = (ra >= 0) ? s1 : s0;
            float val = *sp;
            acc = (vp && vq_[dj]) ? (acc + val) : acc;
        }
    }
    part[tt_] = acc;
    __syncthreads();
    if (tt_ < 256) {
        float s = (part[tt_] + part[tt_ + 256]) + (part[tt_ + 512] + part[tt_ + 768]);
        outmaps[i * 256 + j] = 1.0f / (1.0f + expf(-s));
    }
}

// ---------------- launch ----------------

extern "C" void kernel_launch(void* const* d_in, const int* in_sizes, int n_in,
                              void* d_out, int out_size, void* d_ws, size_t ws_size,
                              hipStream_t stream) {
    const float* att    = (const float*)d_in[0];
    const float* pooled = (const float*)d_in[1];
    const int*   am     = (const int*)d_in[2];
    const float* lin1_w = (const float*)d_in[3];
    const float* lin1_b = (const float*)d_in[4];
    const float* cls_w  = (const float*)d_in[5];
    const float* cls_b  = (const float*)d_in[6];
    const float* c1w    = (const float*)d_in[7];
    const float* c1b    = (const float*)d_in[8];
    const float* c2w    = (const float*)d_in[9];
    const float* c2b    = (const float*)d_in[10];
    float* out = (float*)d_out;
    char*  ws  = (char*)d_ws;

    // workspace (~7.6 MB — featT eliminated)
    __bf16* A1p  = (__bf16*)(ws);                 // 1024*2048*2 = 4,194,304
    __bf16* K2w  = (__bf16*)(ws + 4194304);       // 64*1024*2   =   131,072
    float*  Q    = (float*) (ws + 4325376);       // 49*16384*4  = 3,211,264
    float*  Qs   = (float*) (ws + 7536640);       // 49*256*4    =    50,176  (contiguous with Q)
    float*  Qc   = (float*) (ws + 7586816);       // 49*4 (pad 256)
    int*    rank = (int*)   (ws + 7587072);       // 256*4 (pad 1024)
    float*  hid  = (float*) (ws + 7588096);       // 1024*4
    int*    counts=(int*)   (ws + 7592192);       // 16*4 (pad to 768)
    int*    actg = (int*)   (ws + 7592960);       // 256*4

    k_prep<<<PB_TOTAL, 256, 0, stream>>>(att, am, c1w, c2w, c1b, pooled, lin1_w, lin1_b,
                                         rank, counts, actg, A1p, K2w, Qc, Q, hid);

    gemm_fused<<<dim3(9, 136), 512, 0, stream>>>(A1p, att, actg, K2w, c1b, counts, Q, Qs,
                                                 hid, cls_w, cls_b, out);

    k_out<<<256, 1024, 0, stream>>>(Q, Qs, Qc, rank, counts, c2b, out + 2000);
}

// Round 17
// 151.078 us; speedup vs baseline: 1.7314x; 1.0006x over previous
//
#include <hip/hip_runtime.h>

typedef float  f4v    __attribute__((ext_vector_type(4)));
typedef __bf16 bf16x8 __attribute__((ext_vector_type(8)));
typedef __bf16 bf16x4 __attribute__((ext_vector_type(4)));

#define PCAP  16384   // max pair rows (clamp bound; actual A~127 -> Ppad 8192)
#define LDQ   16384
#define CH    1024
#define KI    2048    // interleaved K (diff/mul alternating)
#define KIT   32      // K iterations (BK=64)

__device__ __forceinline__ int offA(int r, int A) { return r * A - ((r * (r - 1)) >> 1); }

// ballot-scan of mask -> act[], A
__device__ __forceinline__ int mask_scan(const int* am, int t, int* act,
                                         unsigned long long* wm, int* wred) {
    int wave = t >> 6, lane = t & 63;
    int a = am[t];
    int sv = a;
#pragma unroll
    for (int d = 32; d; d >>= 1) sv += __shfl_down(sv, d);
    if (lane == 0) wred[wave] = sv;
    __syncthreads();
    int s = wred[0] + wred[1] + wred[2] + wred[3];
    int keep = (t != 0 && t != s && a != 0) ? 1 : 0;
    unsigned long long bm = __ballot(keep);
    if (lane == 0) wm[wave] = bm;
    __syncthreads();
    int base = 0, A = 0;
#pragma unroll
    for (int w = 0; w < 4; w++) {
        int pc = __popcll(wm[w]);
        if (w < wave) base += pc;
        A += pc;
    }
    if (keep) act[base + __popcll(bm & ((1ull << lane) - 1ull))] = t;
    __syncthreads();
    return A;
}

// ---------------- prep kernel (featT generation fused into gemm) ----------------
#define PB_CVTA   0       // 512: A1p interleaved bf16 conv of conv1_w
#define PB_K2     512     // 256: K2w[64][1024]
#define PB_QCONST 768     // 49
#define PB_ZERO   817     // 797: zero Q + Qs (contiguous)
#define PB_SCAN   1614    // 1: rank/counts/act export
#define PB_HID    1615    // 256: hid gemv
#define PB_TOTAL  1871

__global__ void k_prep(const float* __restrict__ att, const int* __restrict__ am,
                       const float* __restrict__ c1w, const float* __restrict__ c2w,
                       const float* __restrict__ c1b,
                       const float* __restrict__ pooled, const float* __restrict__ lin1_w,
                       const float* __restrict__ lin1_b,
                       int* rank, int* counts, int* actg, __bf16* A1p, __bf16* K2w,
                       float* Qc, float* Qzero, float* hid) {
    int b = blockIdx.x, t = threadIdx.x;

    if (b < PB_K2) {
        int gid = b * 256 + t;              // 131072
        int o = gid >> 7, cw = (gid & 127) * 8;
        const float* wd = &c1w[o * 2048 + cw];
        const float* wmu = &c1w[o * 2048 + 1024 + cw];
        float4 d0 = *(const float4*)wd,  d1 = *(const float4*)(wd + 4);
        float4 m0 = *(const float4*)wmu, m1 = *(const float4*)(wmu + 4);
        bf16x8 v0, v1;
        v0[0] = (__bf16)d0.x; v0[1] = (__bf16)m0.x; v0[2] = (__bf16)d0.y; v0[3] = (__bf16)m0.y;
        v0[4] = (__bf16)d0.z; v0[5] = (__bf16)m0.z; v0[6] = (__bf16)d0.w; v0[7] = (__bf16)m0.w;
        v1[0] = (__bf16)d1.x; v1[1] = (__bf16)m1.x; v1[2] = (__bf16)d1.y; v1[3] = (__bf16)m1.y;
        v1[4] = (__bf16)d1.z; v1[5] = (__bf16)m1.z; v1[6] = (__bf16)d1.w; v1[7] = (__bf16)m1.w;
        *(bf16x8*)&A1p[o * 2048 + 2 * cw] = v0;
        *(bf16x8*)&A1p[o * 2048 + 2 * cw + 8] = v1;
    } else if (b < PB_QCONST) {
        int e = (b - PB_K2) * 256 + t;      // 65536 = 64*1024
        int trow = e >> 10, o = e & 1023;
        K2w[e] = (trow < 49) ? (__bf16)c2w[o * 49 + trow] : (__bf16)0.0f;
    } else if (b < PB_ZERO) {
        __shared__ float sh[256];
        int tap = b - PB_QCONST;
        float s = 0.f;
        for (int o = t; o < CH; o += 256) s += c2w[o * 49 + tap] * fmaxf(c1b[o], 0.f);
        sh[t] = s; __syncthreads();
        for (int d = 128; d; d >>= 1) { if (t < d) sh[t] += sh[t + d]; __syncthreads(); }
        if (t == 0) Qc[tap] = sh[0];
    } else if (b < PB_SCAN) {
        int idx = (b - PB_ZERO) * 256 + t;  // 203840 float4 = Q(49*16384) + Qs(49*256)
        if (idx < 203840) {
            float4 zv = {0.f, 0.f, 0.f, 0.f};
            ((float4*)Qzero)[idx] = zv;
        }
    } else if (b == PB_SCAN) {
        __shared__ int act[256];
        __shared__ unsigned long long wm[4];
        __shared__ int wred[4];
        int A = mask_scan(am, t, act, wm, wred);
        int wave = t >> 6, lane = t & 63;
        int s = wred[0] + wred[1] + wred[2] + wred[3];
        int keep = (t != 0 && t != s && am[t] != 0) ? 1 : 0;
        int base = 0;
#pragma unroll
        for (int w = 0; w < 4; w++) if (w < wave) base += __popcll(wm[w]);
        unsigned long long bm = wm[wave];
        rank[t] = keep ? (base + __popcll(bm & ((1ull << lane) - 1ull))) : -1;
        actg[t] = (t < A) ? act[t] : 0;     // export kept indices for fused gemm
        if (t == 0) {
            int P = (A * (A + 1)) >> 1;
            int Pp = ((P + 127) >> 7) << 7;
            if (Pp > PCAP) Pp = PCAP;
            counts[0] = A; counts[1] = P; counts[2] = Pp;
        }
    } else {
        int o = (b - PB_HID) * 4 + (t >> 6);
        int lane = t & 63;
        const float* row = lin1_w + (size_t)o * CH;
        float s = 0.f;
        for (int c = lane; c < CH; c += 64) s += pooled[c] * row[c];
        for (int d = 32; d; d >>= 1) s += __shfl_down(s, d);
        if (lane == 0) hid[o] = s + lin1_b[o];
    }
}

// ---------------- GEMM, FUSED B-gen, reordered pipeline (pack BEFORE mfma) -----------
// R16 critical path was MFMA -> vmcnt(6) -> PACKB -> lgkm(0) -> barrier: ds_write
// latency + pack VALU fully exposed after the MFMA block. PACKB(kt+1) (buf cur^1) and
// MFMABODY(kt) (buf cur) are INDEPENDENT -> reorder each half-iteration to:
//   vmcnt(0)[att arrived, issued prev iter] -> PACKB -> STAGEA(next)+LOADATT(next+1)
//   -> MFMABODY -> vmcnt(4)+lgkm(0)[A drained, ds_writes drained UNDER the MFMA]
//   -> barrier.
// Unconditional clamped loads (deterministic per-wave vmcnt), named reg sets, math
// identical -> bit-identical output. grid (9,136); x==8: logits gemv.
__global__ __launch_bounds__(512) void gemm_fused(
        const __bf16* __restrict__ A1p, const float* __restrict__ att,
        const int* __restrict__ actg,
        const __bf16* __restrict__ K2w, const float* __restrict__ c1b,
        const int* __restrict__ counts,
        float* __restrict__ Q, float* __restrict__ Qs,
        const float* __restrict__ hid, const float* __restrict__ cls_w,
        const float* __restrict__ cls_b, float* __restrict__ logits) {
    int x = blockIdx.x, y = blockIdx.y;
    int tid = threadIdx.x, wave = tid >> 6, lane = tid & 63;

    if (x == 8) {
#pragma unroll
        for (int rr = 0; rr < 2; rr++) {
            int o = y * 16 + wave * 2 + rr;
            if (o >= 2000) break;
            const float* row = cls_w + (size_t)o * CH;
            float s = 0.f;
            for (int c = lane; c < CH; c += 64) s += hid[c] * row[c];
            for (int d = 32; d; d >>= 1) s += __shfl_down(s, d);
            if (lane == 0) logits[o] = s + cls_b[o];
        }
        return;
    }

    int A = counts[0];
    int P = counts[1]; if (P > PCAP) P = PCAP;
    int Ppad = counts[2];
    int ntp = Ppad >> 7;                 // 128-col pair tiles
    int ntiles = ntp + 2;                // + 2 single tiles (256 rows)
    int c_rt = (ntiles + 7) >> 3;
    int g = (x + y) & 7;                 // XCD id under linear id (x + 9y) % 8
    int nbl = y >> 3, mb = y & 7;
    if (nbl >= c_rt) return;
    int nb = g * c_rt + nbl;
    if (nb >= ntiles) return;
    bool sing = (nb >= ntp);

    __shared__ __align__(16) char smemraw[65536];
    __shared__ int pairs[256];
#define ASP(bsel) ((__bf16(*)[64])(smemraw + (bsel) * 16384))
#define BSP(bsel) ((__bf16(*)[64])(smemraw + 32768 + (bsel) * 16384))
#define HTL ((__bf16(*)[136])(smemraw))
#define K2L ((__bf16(*)[136])(smemraw + 34816))

    // ---- pair setup (once per block): row n -> (i, j); j=-2 for singles,
    // i=-1 for pad rows ----
    if (tid < 128) {
        int i = -1, j = -1;
        if (sing) {
            i = (nb - ntp) * 128 + tid;
            j = -2;
        } else {
            int n = nb * 128 + tid;
            if (n < P && A > 0) {
                float fA = (float)(2 * A + 1);
                float disc = fmaxf(fA * fA - 8.0f * (float)n, 0.0f);
                int r = (int)floorf((fA - sqrtf(disc)) * 0.5f);
                r = min(A - 1, max(0, r));
                while (r > 0 && offA(r, A) > n) --r;
                while (r < A - 1 && offA(r + 1, A) <= n) ++r;
                i = actg[r]; j = actg[r + (n - offA(r, A))];
            }
        }
        pairs[2 * tid] = i; pairs[2 * tid + 1] = j;
    }

    // A staging (pre-swizzled source, linear LDS dest)
    int lanerow = lane >> 3;
    int swchunk = ((lane & 7) ^ lanerow) * 8;
    const __bf16* srcA = A1p + (size_t)(mb * 128 + wave * 16 + lanerow) * KI + swchunk;

    __syncthreads();

    int myrow = tid >> 2, q4 = tid & 3;          // B: 128 rows x 4 quarter-slices
    int pi = pairs[2 * myrow], pj = pairs[2 * myrow + 1];
    const float* attI = att + (size_t)max(pi, 0) * CH;   // clamped: loads always valid
    const float* attJ = att + (size_t)max(pj, 0) * CH;
    bool vi = pi >= 0, vj = pj >= 0;
    int sw0 = ((2 * q4) ^ (myrow & 7)) * 8;      // write-side swizzle == read-side XOR
    int sw1 = ((2 * q4 + 1) ^ (myrow & 7)) * 8;

    f4v acc[4][2] = {};
    int row16 = lane & 15, quad = lane >> 4;
    int wx = wave & 3, wy = wave >> 2;
    float4 zero4 = {0.f, 0.f, 0.f, 0.f};
    float4 eA0, eA1, eB0, eB1, oA0, oA1, oB0, oB1;   // named 2-deep att reg sets

#define STAGEA(kt, bsel)                                                          \
    {                                                                             \
        const __bf16* sA = srcA + (kt) * 64;                                      \
        _Pragma("unroll")                                                         \
        for (int q = 0; q < 2; q++) {                                             \
            __builtin_amdgcn_global_load_lds(                                     \
                (const __attribute__((address_space(1))) void*)(sA + (size_t)q * 8 * KI), \
                (__attribute__((address_space(3))) void*)&ASP(bsel)[wave * 16 + q * 8][0], 16, 0, 0); \
        }                                                                         \
    }

#define LOADATT(kt, rA0, rA1, rB0, rB1)                                           \
    {                                                                             \
        int cb = (kt) * 32 + q4 * 8;                                              \
        rA0 = *(const float4*)&attI[cb];                                          \
        rA1 = *(const float4*)&attI[cb + 4];                                      \
        rB0 = *(const float4*)&attJ[cb];                                          \
        rB1 = *(const float4*)&attJ[cb + 4];                                      \
    }

#define PACKB(bsel, rA0, rA1, rB0, rB1)                                           \
    {                                                                             \
        float4 a0 = vi ? rA0 : zero4, a1 = vi ? rA1 : zero4;                      \
        float4 b0 = vj ? rB0 : zero4, b1 = vj ? rB1 : zero4;                      \
        bf16x8 v0, v1;                                                            \
        v0[0] = (__bf16)fabsf(a0.x - b0.x); v0[1] = (__bf16)(a0.x * b0.x);        \
        v0[2] = (__bf16)fabsf(a0.y - b0.y); v0[3] = (__bf16)(a0.y * b0.y);        \
        v0[4] = (__bf16)fabsf(a0.z - b0.z); v0[5] = (__bf16)(a0.z * b0.z);        \
        v0[6] = (__bf16)fabsf(a0.w - b0.w); v0[7] = (__bf16)(a0.w * b0.w);        \
        v1[0] = (__bf16)fabsf(a1.x - b1.x); v1[1] = (__bf16)(a1.x * b1.x);        \
        v1[2] = (__bf16)fabsf(a1.y - b1.y); v1[3] = (__bf16)(a1.y * b1.y);        \
        v1[4] = (__bf16)fabsf(a1.z - b1.z); v1[5] = (__bf16)(a1.z * b1.z);        \
        v1[6] = (__bf16)fabsf(a1.w - b1.w); v1[7] = (__bf16)(a1.w * b1.w);        \
        *(bf16x8*)&BSP(bsel)[myrow][sw0] = v0;                                    \
        *(bf16x8*)&BSP(bsel)[myrow][sw1] = v1;                                    \
    }

#define MFMABODY(bsel)                                                            \
    _Pragma("unroll")                                                             \
    for (int ks = 0; ks < 2; ks++) {                                              \
        bf16x8 a[4], b[2];                                                        \
        int col = ((ks * 4 + quad) ^ (row16 & 7)) * 8;                            \
        _Pragma("unroll")                                                         \
        for (int mt = 0; mt < 4; mt++)                                            \
            a[mt] = *(const bf16x8*)&ASP(bsel)[wy * 64 + mt * 16 + row16][col];   \
        _Pragma("unroll")                                                         \
        for (int nt = 0; nt < 2; nt++)                                            \
            b[nt] = *(const bf16x8*)&BSP(bsel)[wx * 32 + nt * 16 + row16][col];   \
        _Pragma("unroll")                                                         \
        for (int mt = 0; mt < 4; mt++)                                            \
            _Pragma("unroll")                                                     \
            for (int nt = 0; nt < 2; nt++)                                        \
                acc[mt][nt] = __builtin_amdgcn_mfma_f32_16x16x32_bf16(a[mt], b[nt], acc[mt][nt], 0, 0, 0); \
    }

    // ---- prologue: buf0 <- tile 0; attO(1) in flight at loop entry ----
    LOADATT(0, eA0, eA1, eB0, eB1);      // attE(0)x4
    STAGEA(0, 0);                        // A(0)x2
    __builtin_amdgcn_s_waitcnt(0xF72);   // drain attE(0) (oldest 4); A(0)x2 in flight
    PACKB(0, eA0, eA1, eB0, eB1);
    LOADATT(1, oA0, oA1, oB0, oB1);      // attO(1)x4 -> in flight: A(0)x2 + attO(1)x4
    __builtin_amdgcn_s_waitcnt(0x074);   // vmcnt(4)+lgkm(0): drain A(0); keep attO(1)
    __builtin_amdgcn_s_barrier();

    // ---- main loop: tiles (kt, kt+1), kt = 0..28 ----
    for (int kt = 0; kt < 30; kt += 2) {
        // even half: MFMA tile kt (buf0); pack tile kt+1 (buf1) from O regs
        __builtin_amdgcn_s_waitcnt(0xF70);        // attO(kt+1) arrived (issued prev half)
        PACKB(1, oA0, oA1, oB0, oB1);
        STAGEA(kt + 1, 1);                        // A(kt+1)x2
        LOADATT(kt + 2, eA0, eA1, eB0, eB1);      // attE(kt+2)x4
        MFMABODY(0);
        __builtin_amdgcn_s_waitcnt(0x074);        // drain A(kt+1)+ds_writes; keep attE(kt+2)
        __builtin_amdgcn_s_barrier();
        // odd half: MFMA tile kt+1 (buf1); pack tile kt+2 (buf0) from E regs
        __builtin_amdgcn_s_waitcnt(0xF70);        // attE(kt+2) arrived
        PACKB(0, eA0, eA1, eB0, eB1);
        STAGEA(kt + 2, 0);                        // A(kt+2)x2
        LOADATT(kt + 3, oA0, oA1, oB0, oB1);      // attO(kt+3)x4
        MFMABODY(1);
        __builtin_amdgcn_s_waitcnt(0x074);        // drain A(kt+2)+ds_writes; keep attO(kt+3)
        __builtin_amdgcn_s_barrier();
    }
    // tail: tile 30 in buf0; attO(31)x4 in flight
    __builtin_amdgcn_s_waitcnt(0xF70);            // attO(31) arrived
    PACKB(1, oA0, oA1, oB0, oB1);
    STAGEA(31, 1);                                // A(31)x2
    MFMABODY(0);
    __builtin_amdgcn_s_waitcnt(0x070);            // vmcnt(0)+lgkm(0): A(31)+writes done
    __builtin_amdgcn_s_barrier();
    // tail: tile 31
    MFMABODY(1);
    __syncthreads();
#undef STAGEA
#undef LOADATT
#undef PACKB
#undef MFMABODY

    // ---- phase 2: K2 tile + relu(h) tile in LDS, contract 128 local o's ----
#pragma unroll
    for (int it = 0; it < 2; it++) {
        int gid = it * 512 + tid;                  // 1024 = 64 rows x 16 chunks
        int trow = gid >> 4, oc = (gid & 15) * 8;
        bf16x8 kv = *(const bf16x8*)&K2w[(size_t)trow * CH + mb * 128 + oc];
        *(bf16x8*)&K2L[trow][oc] = kv;
    }
#pragma unroll
    for (int mt = 0; mt < 4; mt++) {
        int ol = wy * 64 + mt * 16 + quad * 4;
        float4 bv = *(const float4*)&c1b[mb * 128 + ol];
#pragma unroll
        for (int nt = 0; nt < 2; nt++) {
            int n = wx * 32 + nt * 16 + row16;
            bf16x4 pk;
            pk[0] = (__bf16)fmaxf(acc[mt][nt][0] + bv.x, 0.f);
            pk[1] = (__bf16)fmaxf(acc[mt][nt][1] + bv.y, 0.f);
            pk[2] = (__bf16)fmaxf(acc[mt][nt][2] + bv.z, 0.f);
            pk[3] = (__bf16)fmaxf(acc[mt][nt][3] + bv.w, 0.f);
            *(bf16x4*)&HTL[n][ol] = pk;
        }
    }
    __syncthreads();

    int tq = wave & 3, nhalf = wave >> 2;
    f4v acc2[4] = {};
#pragma unroll
    for (int ko = 0; ko < 4; ko++) {
        bf16x8 af = *(const bf16x8*)&K2L[tq * 16 + row16][ko * 32 + quad * 8];
#pragma unroll
        for (int nt = 0; nt < 4; nt++) {
            bf16x8 bf_ = *(const bf16x8*)&HTL[nhalf * 64 + nt * 16 + row16][ko * 32 + quad * 8];
            acc2[nt] = __builtin_amdgcn_mfma_f32_16x16x32_bf16(af, bf_, acc2[nt], 0, 0, 0);
        }
    }

    float* Qdst = sing ? Qs : Q;
    int ldq = sing ? 256 : LDQ;
    int nbase = sing ? (nb - ntp) * 128 : nb * 128;
    int t0 = tq * 16 + quad * 4;
#pragma unroll
    for (int nt = 0; nt < 4; nt++) {
        int n = nbase + nhalf * 64 + nt * 16 + row16;
#pragma unroll
        for (int r = 0; r < 4; r++)
            if (t0 + r < 49) atomicAdd(&Qdst[(size_t)(t0 + r) * ldq + n], acc2[nt][r]);
    }
#undef ASP
#undef BSP
#undef HTL
#undef K2L
}

// ---------------- output: 1024 threads, 4-way tap split, branchless gather -----------
__global__ __launch_bounds__(1024) void k_out(
                      const float* __restrict__ Q, const float* __restrict__ Qs,
                      const float* __restrict__ Qc, const int* __restrict__ rank,
                      const int* __restrict__ counts, const float* b2,
                      float* __restrict__ outmaps) {
    __shared__ int rankL[256];
    __shared__ float part[1024];
    int tt_ = threadIdx.x, i = blockIdx.x;
    int t = tt_ & 255;
    int quarter = tt_ >> 8;
    if (tt_ < 256) rankL[tt_] = rank[tt_];
    __syncthreads();
    int A = counts[0];
    int j = t;

    int qc_[7], rq_[7], oq_[7];
    bool vq_[7];
#pragma unroll
    for (int dj = 0; dj < 7; dj++) {
        int q = j + dj - 3;
        vq_[dj] = ((unsigned)q <= 255u);
        int qc = min(255, max(0, q));
        qc_[dj] = qc;
        int r = rankL[qc];
        rq_[dj] = r;
        oq_[dj] = offA(max(r, 0), A);
    }

    float acc = (quarter == 0) ? b2[0] : 0.f;
#pragma unroll
    for (int di = 0; di < 7; di++) {
        int p = i + di - 3;                      // block-uniform
        bool vp = ((unsigned)p <= 255u);
        int pc = min(255, max(0, p));
        int rp = rankL[pc];
        int op = offA(max(rp, 0), A);
#pragma unroll
        for (int dj = 0; dj < 7; dj++) {
            int tt = di * 7 + dj;
            if ((tt & 3) != quarter) continue;   // compile-time tt, wave-uniform quarter
            int qc = qc_[dj];
            bool pfirst = (pc <= qc);
            int a  = pfirst ? pc : qc;
            int bb = pfirst ? qc : pc;
            int ra = pfirst ? rp : rq_[dj];
            int rb = pfirst ? rq_[dj] : rp;
            int oa = pfirst ? op : oq_[dj];
            const float* s1 = (rb >= 0) ? (Q + (size_t)tt * LDQ + (oa + rb - ra))
                                        : (Qs + tt * 256 + a);
            const float* s0 = (rb >= 0) ? (Qs + tt * 256 + bb)
                                        : (Qc + tt);
            const float* sp = (ra >= 0) ? s1 : s0;
            float val = *sp;
            acc = (vp && vq_[dj]) ? (acc + val) : acc;
        }
    }
    part[tt_] = acc;
    __syncthreads();
    if (tt_ < 256) {
        float s = (part[tt_] + part[tt_ + 256]) + (part[tt_ + 512] + part[tt_ + 768]);
        outmaps[i * 256 + j] = 1.0f / (1.0f + expf(-s));
    }
}

// ---------------- launch ----------------

extern "C" void kernel_launch(void* const* d_in, const int* in_sizes, int n_in,
                              void* d_out, int out_size, void* d_ws, size_t ws_size,
                              hipStream_t stream) {
    const float* att    = (const float*)d_in[0];
    const float* pooled = (const float*)d_in[1];
    const int*   am     = (const int*)d_in[2];
    const float* lin1_w = (const float*)d_in[3];
    const float* lin1_b = (const float*)d_in[4];
    const float* cls_w  = (const float*)d_in[5];
    const float* cls_b  = (const float*)d_in[6];
    const float* c1w    = (const float*)d_in[7];
    const float* c1b    = (const float*)d_in[8];
    const float* c2w    = (const float*)d_in[9];
    const float* c2b    = (const float*)d_in[10];
    float* out = (float*)d_out;
    char*  ws  = (char*)d_ws;

    // workspace (~7.6 MB — featT eliminated)
    __bf16* A1p  = (__bf16*)(ws);                 // 1024*2048*2 = 4,194,304
    __bf16* K2w  = (__bf16*)(ws + 4194304);       // 64*1024*2   =   131,072
    float*  Q    = (float*) (ws + 4325376);       // 49*16384*4  = 3,211,264
    float*  Qs   = (float*) (ws + 7536640);       // 49*256*4    =    50,176  (contiguous with Q)
    float*  Qc   = (float*) (ws + 7586816);       // 49*4 (pad 256)
    int*    rank = (int*)   (ws + 7587072);       // 256*4 (pad 1024)
    float*  hid  = (float*) (ws + 7588096);       // 1024*4
    int*    counts=(int*)   (ws + 7592192);       // 16*4 (pad to 768)
    int*    actg = (int*)   (ws + 7592960);       // 256*4

    k_prep<<<PB_TOTAL, 256, 0, stream>>>(att, am, c1w, c2w, c1b, pooled, lin1_w, lin1_b,
                                         rank, counts, actg, A1p, K2w, Qc, Q, hid);

    gemm_fused<<<dim3(9, 136), 512, 0, stream>>>(A1p, att, actg, K2w, c1b, counts, Q, Qs,
                                                 hid, cls_w, cls_b, out);

    k_out<<<256, 1024, 0, stream>>>(Q, Qs, Qc, rank, counts, c2b, out + 2000);
}